// Round 10
// baseline (215.266 us; speedup 1.0000x reference)
//
#include <hip/hip_runtime.h>

#define DIMK 64
#define MC 256
#define NROWS 262144
#define NSTRIPS (NROWS / 32)          // 8192 strips of 32 rows
#define K1B 512                       // k1 persistent blocks (2/CU)
#define K1W 4                         // waves per k1 block
#define K1I (NSTRIPS / (K1B * K1W))   // 4 strips per wave
#define K2B 2048
#define K2IT (NROWS * DIMK / 4 / (K2B * 256))   // 8 float4 per thread

// workspace layout (bytes):
//   [0, 1024)              cvec fp32 (256 floats)              [always]
//   [1024, 66560)          At fp16 hi/lo plane-major image     [tier >= AT]
//       hi at WS_AT + ((s*4 + kc)*256 + col)*16, kc = 2*ksl + hi; lo at +32768
//   [66560, 66560+1 MB)    gm[N] fp32                          [tier SPLIT]
#define WS_AT 1024
#define WS_GM (WS_AT + 65536)
#define WS_NEED_SPLIT (WS_GM + NROWS * 4)

// fallback LDS offsets (round-3 proven layout)
#define LDS_AH 0
#define LDS_AL 16384
#define LDS_GM 32768

typedef _Float16 half8 __attribute__((ext_vector_type(8)));
typedef float f32x16 __attribute__((ext_vector_type(16)));
typedef float f32x4 __attribute__((ext_vector_type(4)));   // clang-native for NT store

__device__ __forceinline__ void cvt_half8(const float* v, half8& h, half8& l) {
#pragma unroll
    for (int j = 0; j < 8; ++j) {
        h[j] = (_Float16)v[j];
        l[j] = (_Float16)(v[j] - (float)h[j]);
    }
}

// cvec only (1 KB ws — proven-safe footprint)
__global__ void precompute_c(const float* __restrict__ pivot,
                             const float* __restrict__ At,
                             float* __restrict__ ws) {
    const int t = threadIdx.x;
    float acc = 0.f;
#pragma unroll
    for (int k = 0; k < DIMK; ++k) acc = fmaf(pivot[k], At[k * MC + t], acc);
    ws[t] = acc;
}

// cvec + one-time At -> fp16 hi/lo split, plane-major image
__global__ void precompute_at(const float* __restrict__ pivot,
                              const float* __restrict__ At,
                              float* __restrict__ ws) {
    const int t = threadIdx.x;              // column 0..255
    float col[DIMK];
    float acc = 0.f;
#pragma unroll
    for (int k = 0; k < DIMK; ++k) {
        col[k] = At[k * MC + t];            // coalesced across t
        acc = fmaf(pivot[k], col[k], acc);
    }
    ws[t] = acc;                            // cvec, fp32
    char* wsb = (char*)ws + WS_AT;
#pragma unroll
    for (int s = 0; s < 2; ++s) {
#pragma unroll
        for (int kc = 0; kc < 4; ++kc) {
            half8 h, l;
#pragma unroll
            for (int j = 0; j < 8; ++j) {
                const float v = col[s * 32 + kc * 8 + j];
                h[j] = (_Float16)v;
                l[j] = (_Float16)(v - (float)h[j]);
            }
            const int off = ((s * 4 + kc) * 256 + t) * 16;
            *(half8*)(wsb + off) = h;
            *(half8*)(wsb + off + 32768) = l;
        }
    }
}

// ============ K1: GEMM + in-wave row-max -> gm[N] ============================
// Sequential col-tile accumulation: one f32x16 acc live at a time (no spill).
__global__ __launch_bounds__(256, 2)
void k1_gemm_rowmax(const float* __restrict__ z,
                    const float* __restrict__ b,
                    const float* __restrict__ ws,
                    float* __restrict__ gmv) {
    __shared__ __align__(16) char lds[65536];

    const int tid  = threadIdx.x;
    const int lane = tid & 63;
    const int li   = lane & 31;
    const int hi   = lane >> 5;
    const int wid  = tid >> 6;

    // stage full At image into LDS once (coalesced float4 linear copy)
    {
        const char* wsA = (const char*)ws + WS_AT;
#pragma unroll
        for (int p = 0; p < 16; ++p) {
            const int f = p * 256 + tid;
            *(float4*)(lds + f * 16) = *(const float4*)(wsA + f * 16);
        }
    }
    // per-lane constants for all 256 cols (col = ct*32 + li)
    float bv[8], cv[8];
#pragma unroll
    for (int ct = 0; ct < 8; ++ct) {
        bv[ct] = b[ct * 32 + li];
        cv[ct] = ws[ct * 32 + li];          // cvec fp32
    }
    __syncthreads();                        // the only barrier

    auto zload = [&](float4 (&zb)[8], const int strip) {
        const float* zr = z + (strip * 32 + li) * DIMK + hi * 8;
        zb[0] = *(const float4*)(zr);      zb[1] = *(const float4*)(zr + 4);
        zb[2] = *(const float4*)(zr + 16); zb[3] = *(const float4*)(zr + 20);
        zb[4] = *(const float4*)(zr + 32); zb[5] = *(const float4*)(zr + 36);
        zb[6] = *(const float4*)(zr + 48); zb[7] = *(const float4*)(zr + 52);
    };

    float4 zb[8];
    zload(zb, blockIdx.x * (K1W * K1I) + wid);

    const int ldsbase = hi * 4096 + li * 16;

#pragma clang loop unroll(disable)
    for (int it = 0; it < K1I; ++it) {
        const int strip = blockIdx.x * (K1W * K1I) + it * K1W + wid;

        // convert current strip's z to fp16 hi/lo fragments
        half8 azh[4], azl[4];
#pragma unroll
        for (int q = 0; q < 4; ++q)
            cvt_half8((const float*)&zb[q * 2], azh[q], azl[q]);

        // zb registers are dead now — prefetch next strip (hidden under MFMA)
        if (it < K1I - 1) zload(zb, strip + K1W);

        float gm[16];
#pragma unroll
        for (int r = 0; r < 16; ++r) gm[r] = 0.f;

        // one column-tile at a time: acc lives only inside the ct iteration
#pragma unroll
        for (int ct = 0; ct < 8; ++ct) {
            f32x16 acc;
#pragma unroll
            for (int e = 0; e < 16; ++e) acc[e] = 0.f;

#pragma unroll
            for (int st = 0; st < 4; ++st) {
                const int ob = (st >> 1) * 16384 + (st & 1) * 8192 +
                               ldsbase + ct * 512;
                const half8 bh = *(const half8*)(lds + ob);
                const half8 bl = *(const half8*)(lds + ob + 32768);
                const half8 ah = azh[st], al = azl[st];
                acc = __builtin_amdgcn_mfma_f32_32x32x16_f16(ah, bh, acc, 0, 0, 0);
                acc = __builtin_amdgcn_mfma_f32_32x32x16_f16(ah, bl, acc, 0, 0, 0);
                acc = __builtin_amdgcn_mfma_f32_32x32x16_f16(al, bh, acc, 0, 0, 0);
            }

            // fold this tile into the running row-max (VALU overlaps next MFMA)
#pragma unroll
            for (int r = 0; r < 16; ++r) {
                const float sv = acc[r];
                const float sa = sv - bv[ct];
                const float qd = fmaxf(sv - cv[ct], 1e-9f);
                // sa<0 gives very negative alpha, excluded by fmax (gm>=0)
                gm[r] = fmaxf(gm[r], sa * __builtin_amdgcn_rcpf(qd));
            }
        }

        // full 256-col row-max: reduce over the 32 col-lanes
#pragma unroll
        for (int r = 0; r < 16; ++r)
#pragma unroll
            for (int off = 1; off < 32; off <<= 1)
                gm[r] = fmaxf(gm[r], __shfl_xor(gm[r], off));

        if (li == 0) {
#pragma unroll
            for (int r = 0; r < 16; ++r) {
                const int row = (r & 3) + 8 * (r >> 2) + 4 * hi;  // C/D row map
                gmv[strip * 32 + row] = gm[r];
            }
        }
    }
}

// ============ K2: streaming apply out = z + gm*(pivot - z) ==================
__global__ __launch_bounds__(256)
void k2_apply(const float* __restrict__ z,
              const float* __restrict__ pivot,
              const float* __restrict__ gmv,
              float* __restrict__ out) {
    const int t = blockIdx.x * 256 + threadIdx.x;
    const f32x4 pv = ((const f32x4*)pivot)[t & 15];     // lane-invariant d-slice
#pragma unroll
    for (int it = 0; it < K2IT; ++it) {
        const int i = t + it * (K2B * 256);             // float4 index
        const float g = gmv[i >> 4];                    // row = (i*4)/64
        const f32x4 z4 = ((const f32x4*)z)[i];
        f32x4 o;
        o.x = fmaf(g, pv.x - z4.x, z4.x);
        o.y = fmaf(g, pv.y - z4.y, z4.y);
        o.z = fmaf(g, pv.z - z4.z, z4.z);
        o.w = fmaf(g, pv.w - z4.w, z4.w);
        __builtin_nontemporal_store(o, &((f32x4*)out)[i]);
    }
}

// ============ fallback: round-3-style single fused kernel (proven) ==========
__global__ __launch_bounds__(256, 4)
void fused_constrain_fb(const float* __restrict__ z,
                        const float* __restrict__ pivot,
                        const float* __restrict__ At,
                        const float* __restrict__ b,
                        const float* __restrict__ ws,
                        float* __restrict__ out) {
    __shared__ __align__(16) char lds[33280];

    const int tid  = threadIdx.x;
    const int lane = tid & 63;
    const int li   = lane & 31;
    const int hi   = lane >> 5;
    const int wid  = tid >> 6;
    const int rg   = wid >> 1;
    const int cg   = wid & 1;
    const int R0   = rg * 32;
    const int colbase = cg * 128;
    const int base = blockIdx.x * (64 * DIMK);

    float4 zf[8];
    {
        const float* zr = z + base + (R0 + li) * DIMK + hi * 8;
#pragma unroll
        for (int q = 0; q < 4; ++q) {
            const float* p = zr + (q >> 1) * 32 + (q & 1) * 16;
            zf[q * 2 + 0] = *(const float4*)(p);
            zf[q * 2 + 1] = *(const float4*)(p + 4);
        }
    }
    const int swzT = (tid & 3) ^ ((tid >> 2) & 3);
#pragma unroll
    for (int kc = 0; kc < 4; ++kc) {
        float v[8];
#pragma unroll
        for (int j = 0; j < 8; ++j) v[j] = At[(kc * 8 + j) * MC + tid];
        half8 h, l;
#pragma unroll
        for (int j = 0; j < 8; ++j) {
            h[j] = (_Float16)v[j];
            l[j] = (_Float16)(v[j] - (float)h[j]);
        }
        const int off = tid * 64 + ((kc ^ swzT) << 4);
        *(half8*)(lds + LDS_AH + off) = h;
        *(half8*)(lds + LDS_AL + off) = l;
    }

    half8 azh[4], azl[4];
    const float* zv = (const float*)zf;
#pragma unroll
    for (int q = 0; q < 4; ++q)
        cvt_half8(zv + q * 8, azh[q], azl[q]);

    f32x16 acc[4];
#pragma unroll
    for (int ct = 0; ct < 4; ++ct)
#pragma unroll
        for (int e = 0; e < 16; ++e) acc[ct][e] = 0.f;

    const int swz = (li & 3) ^ ((li >> 2) & 3);
    __syncthreads();
#pragma unroll
    for (int ksl = 0; ksl < 2; ++ksl) {
        const int cb = ((ksl * 2 + hi) ^ swz) << 4;
        const half8 ah = azh[ksl], al = azl[ksl];
#pragma unroll
        for (int ct = 0; ct < 4; ++ct) {
            const int off = (colbase + ct * 32 + li) * 64 + cb;
            const half8 bh = *(const half8*)(lds + LDS_AH + off);
            const half8 bl = *(const half8*)(lds + LDS_AL + off);
            acc[ct] = __builtin_amdgcn_mfma_f32_32x32x16_f16(ah, bh, acc[ct], 0, 0, 0);
            acc[ct] = __builtin_amdgcn_mfma_f32_32x32x16_f16(ah, bl, acc[ct], 0, 0, 0);
            acc[ct] = __builtin_amdgcn_mfma_f32_32x32x16_f16(al, bh, acc[ct], 0, 0, 0);
        }
    }
    __syncthreads();
#pragma unroll
    for (int kc = 0; kc < 4; ++kc) {
        float v[8];
#pragma unroll
        for (int j = 0; j < 8; ++j) v[j] = At[(32 + kc * 8 + j) * MC + tid];
        half8 h, l;
#pragma unroll
        for (int j = 0; j < 8; ++j) {
            h[j] = (_Float16)v[j];
            l[j] = (_Float16)(v[j] - (float)h[j]);
        }
        const int off = tid * 64 + ((kc ^ swzT) << 4);
        *(half8*)(lds + LDS_AH + off) = h;
        *(half8*)(lds + LDS_AL + off) = l;
    }
    __syncthreads();
#pragma unroll
    for (int ksl = 0; ksl < 2; ++ksl) {
        const int cb = ((ksl * 2 + hi) ^ swz) << 4;
        const half8 ah = azh[2 + ksl], al = azl[2 + ksl];
#pragma unroll
        for (int ct = 0; ct < 4; ++ct) {
            const int off = (colbase + ct * 32 + li) * 64 + cb;
            const half8 bh = *(const half8*)(lds + LDS_AH + off);
            const half8 bl = *(const half8*)(lds + LDS_AL + off);
            acc[ct] = __builtin_amdgcn_mfma_f32_32x32x16_f16(ah, bh, acc[ct], 0, 0, 0);
            acc[ct] = __builtin_amdgcn_mfma_f32_32x32x16_f16(ah, bl, acc[ct], 0, 0, 0);
            acc[ct] = __builtin_amdgcn_mfma_f32_32x32x16_f16(al, bh, acc[ct], 0, 0, 0);
        }
    }

    float bv[4], cv[4];
#pragma unroll
    for (int ct = 0; ct < 4; ++ct) {
        const int c = colbase + ct * 32 + li;
        bv[ct] = b[c];
        cv[ct] = ws[c];
    }
    float gm[16];
#pragma unroll
    for (int r = 0; r < 16; ++r) gm[r] = 0.f;
#pragma unroll
    for (int ct = 0; ct < 4; ++ct)
#pragma unroll
        for (int r = 0; r < 16; ++r) {
            const float sv = acc[ct][r];
            const float sa = sv - bv[ct];
            const float qd = fmaxf(sv - cv[ct], 1e-9f);
            gm[r] = fmaxf(gm[r], sa * __builtin_amdgcn_rcpf(qd));
        }
#pragma unroll
    for (int r = 0; r < 16; ++r)
#pragma unroll
        for (int off = 1; off < 32; off <<= 1)
            gm[r] = fmaxf(gm[r], __shfl_xor(gm[r], off));

    float* gmbuf = (float*)(lds + LDS_GM);
#pragma unroll
    for (int r = 0; r < 16; ++r) {
        const int row = (r & 3) + 8 * (r >> 2) + 4 * hi;
        if (li == 0) gmbuf[rg * 64 + row * 2 + cg] = gm[r];
    }
    __syncthreads();

    const float2 p2 = *(const float2*)(pivot + 2 * li);
    const int r0 = cg * 8;
#pragma unroll
    for (int rr = 0; rr < 8; ++rr) {
        const int r   = r0 + rr;
        const int row = (r & 3) + 8 * (r >> 2) + 4 * hi;
        const float g = fmaxf(gm[r], gmbuf[rg * 64 + row * 2 + (cg ^ 1)]);
        const int idx = base + (R0 + row) * DIMK + 2 * li;
        const float2 zz = *(const float2*)(z + idx);
        float2 o;
        o.x = fmaf(g, p2.x - zz.x, zz.x);
        o.y = fmaf(g, p2.y - zz.y, zz.y);
        *(float2*)(out + idx) = o;
    }
}

extern "C" void kernel_launch(void* const* d_in, const int* in_sizes, int n_in,
                              void* d_out, int out_size, void* d_ws, size_t ws_size,
                              hipStream_t stream) {
    const float* z     = (const float*)d_in[0];
    const float* pivot = (const float*)d_in[1];
    const float* At    = (const float*)d_in[2];
    const float* b     = (const float*)d_in[3];
    float* ws = (float*)d_ws;
    if (ws_size >= (size_t)WS_NEED_SPLIT) {
        // split path: barrier-free GEMM+rowmax (no spill), streaming apply
        float* gmv = (float*)((char*)d_ws + WS_GM);
        precompute_at<<<dim3(1), dim3(MC), 0, stream>>>(pivot, At, ws);
        k1_gemm_rowmax<<<dim3(K1B), dim3(256), 0, stream>>>(z, b, ws, gmv);
        k2_apply<<<dim3(K2B), dim3(256), 0, stream>>>(z, pivot, gmv,
                                                      (float*)d_out);
    } else {
        // safe path: 1 KB ws (cvec); per-block At split (proven structure)
        precompute_c<<<dim3(1), dim3(MC), 0, stream>>>(pivot, At, ws);
        fused_constrain_fb<<<dim3(NROWS / 64), dim3(256), 0, stream>>>(
            z, pivot, At, b, ws, (float*)d_out);
    }
}

// Round 11
// 154.356 us; speedup vs baseline: 1.3946x; 1.3946x over previous
//
#include <hip/hip_runtime.h>

#define DIMK 64
#define MC 256
#define NROWS 262144
#define NSTRIPS (NROWS / 32)          // 8192 strips of 32 rows
#define K1B 512                       // k1 persistent blocks (2/CU)
#define K1W 4                         // waves per k1 block
#define K1I (NSTRIPS / (K1B * K1W))   // 4 strips per wave
#define K2B 2048
#define K2IT (NROWS * DIMK / 4 / (K2B * 256))   // 8 float4 per thread

// workspace layout (bytes):
//   [0, 1024)              cvec fp32 (256 floats)              [always]
//   [1024, 66560)          At fp16 hi/lo plane-major image     [tier >= AT]
//       hi at WS_AT + ((s*4 + kc)*256 + col)*16, kc = 2*ksl + hi; lo at +32768
//   [66560, 66560+1 MB)    gm[N] fp32                          [tier SPLIT]
#define WS_AT 1024
#define WS_GM (WS_AT + 65536)
#define WS_NEED_SPLIT (WS_GM + NROWS * 4)

// fallback LDS offsets (round-3 proven layout)
#define LDS_AH 0
#define LDS_AL 16384
#define LDS_GM 32768

typedef _Float16 half8 __attribute__((ext_vector_type(8)));
typedef float f32x16 __attribute__((ext_vector_type(16)));
typedef float f32x4 __attribute__((ext_vector_type(4)));   // clang-native for NT store

__device__ __forceinline__ void cvt_half8(const float* v, half8& h, half8& l) {
#pragma unroll
    for (int j = 0; j < 8; ++j) {
        h[j] = (_Float16)v[j];
        l[j] = (_Float16)(v[j] - (float)h[j]);
    }
}

// cvec only (1 KB ws — proven-safe footprint)
__global__ void precompute_c(const float* __restrict__ pivot,
                             const float* __restrict__ At,
                             float* __restrict__ ws) {
    const int t = threadIdx.x;
    float acc = 0.f;
#pragma unroll
    for (int k = 0; k < DIMK; ++k) acc = fmaf(pivot[k], At[k * MC + t], acc);
    ws[t] = acc;
}

// cvec + one-time At -> fp16 hi/lo split, plane-major image
__global__ void precompute_at(const float* __restrict__ pivot,
                              const float* __restrict__ At,
                              float* __restrict__ ws) {
    const int t = threadIdx.x;              // column 0..255
    float col[DIMK];
    float acc = 0.f;
#pragma unroll
    for (int k = 0; k < DIMK; ++k) {
        col[k] = At[k * MC + t];            // coalesced across t
        acc = fmaf(pivot[k], col[k], acc);
    }
    ws[t] = acc;                            // cvec, fp32
    char* wsb = (char*)ws + WS_AT;
#pragma unroll
    for (int s = 0; s < 2; ++s) {
#pragma unroll
        for (int kc = 0; kc < 4; ++kc) {
            half8 h, l;
#pragma unroll
            for (int j = 0; j < 8; ++j) {
                const float v = col[s * 32 + kc * 8 + j];
                h[j] = (_Float16)v;
                l[j] = (_Float16)(v - (float)h[j]);
            }
            const int off = ((s * 4 + kc) * 256 + t) * 16;
            *(half8*)(wsb + off) = h;
            *(half8*)(wsb + off + 32768) = l;
        }
    }
}

// ============ K1: GEMM + in-wave row-max -> gm[N] ============================
// Sequential col-tile accumulation enforced with sched_barrier(0): only one
// f32x16 acc live at a time -> no spill (R9: 128-AGPR acc spilled 37 MB;
// R10: unroll+scheduler interleave spilled 78 MB).
__global__ __launch_bounds__(256, 2)
void k1_gemm_rowmax(const float* __restrict__ z,
                    const float* __restrict__ b,
                    const float* __restrict__ ws,
                    float* __restrict__ gmv) {
    __shared__ __align__(16) char lds[65536];

    const int tid  = threadIdx.x;
    const int lane = tid & 63;
    const int li   = lane & 31;
    const int hi   = lane >> 5;
    const int wid  = tid >> 6;

    // stage full At image into LDS once (coalesced float4 linear copy)
    {
        const char* wsA = (const char*)ws + WS_AT;
#pragma unroll
        for (int p = 0; p < 16; ++p) {
            const int f = p * 256 + tid;
            *(float4*)(lds + f * 16) = *(const float4*)(wsA + f * 16);
        }
    }
    // per-lane constants for all 256 cols (col = ct*32 + li)
    float bv[8], cv[8];
#pragma unroll
    for (int ct = 0; ct < 8; ++ct) {
        bv[ct] = b[ct * 32 + li];
        cv[ct] = ws[ct * 32 + li];          // cvec fp32
    }
    __syncthreads();                        // the only barrier

    auto zload = [&](float4 (&zb)[8], const int strip) {
        const float* zr = z + (strip * 32 + li) * DIMK + hi * 8;
        zb[0] = *(const float4*)(zr);      zb[1] = *(const float4*)(zr + 4);
        zb[2] = *(const float4*)(zr + 16); zb[3] = *(const float4*)(zr + 20);
        zb[4] = *(const float4*)(zr + 32); zb[5] = *(const float4*)(zr + 36);
        zb[6] = *(const float4*)(zr + 48); zb[7] = *(const float4*)(zr + 52);
    };

    float4 zb[8];
    zload(zb, blockIdx.x * (K1W * K1I) + wid);

    const int ldsbase = hi * 4096 + li * 16;

#pragma clang loop unroll(disable)
    for (int it = 0; it < K1I; ++it) {
        const int strip = blockIdx.x * (K1W * K1I) + it * K1W + wid;

        // convert current strip's z to fp16 hi/lo fragments
        half8 azh[4], azl[4];
#pragma unroll
        for (int q = 0; q < 4; ++q)
            cvt_half8((const float*)&zb[q * 2], azh[q], azl[q]);

        // zb registers are dead now — prefetch next strip (hidden under MFMA)
        if (it < K1I - 1) zload(zb, strip + K1W);

        float gm[16];
#pragma unroll
        for (int r = 0; r < 16; ++r) gm[r] = 0.f;

        // one column-tile at a time; sched_barrier(0) fences each iteration so
        // the scheduler cannot interleave ct's (live-range / spill control)
#pragma unroll
        for (int ct = 0; ct < 8; ++ct) {
            f32x16 acc;
#pragma unroll
            for (int e = 0; e < 16; ++e) acc[e] = 0.f;

#pragma unroll
            for (int st = 0; st < 4; ++st) {
                const int ob = (st >> 1) * 16384 + (st & 1) * 8192 +
                               ldsbase + ct * 512;
                const half8 bh = *(const half8*)(lds + ob);
                const half8 bl = *(const half8*)(lds + ob + 32768);
                const half8 ah = azh[st], al = azl[st];
                acc = __builtin_amdgcn_mfma_f32_32x32x16_f16(ah, bh, acc, 0, 0, 0);
                acc = __builtin_amdgcn_mfma_f32_32x32x16_f16(ah, bl, acc, 0, 0, 0);
                acc = __builtin_amdgcn_mfma_f32_32x32x16_f16(al, bh, acc, 0, 0, 0);
            }

            // fold this tile into the running row-max
#pragma unroll
            for (int r = 0; r < 16; ++r) {
                const float sv = acc[r];
                const float sa = sv - bv[ct];
                const float qd = fmaxf(sv - cv[ct], 1e-9f);
                // sa<0 gives very negative alpha, excluded by fmax (gm>=0)
                gm[r] = fmaxf(gm[r], sa * __builtin_amdgcn_rcpf(qd));
            }

            __builtin_amdgcn_sched_barrier(0);   // fence: acc dies here
        }

        // full 256-col row-max: reduce over the 32 col-lanes
#pragma unroll
        for (int r = 0; r < 16; ++r)
#pragma unroll
            for (int off = 1; off < 32; off <<= 1)
                gm[r] = fmaxf(gm[r], __shfl_xor(gm[r], off));

        if (li == 0) {
#pragma unroll
            for (int r = 0; r < 16; ++r) {
                const int row = (r & 3) + 8 * (r >> 2) + 4 * hi;  // C/D row map
                gmv[strip * 32 + row] = gm[r];
            }
        }
    }
}

// ============ K2: streaming apply out = z + gm*(pivot - z) ==================
__global__ __launch_bounds__(256)
void k2_apply(const float* __restrict__ z,
              const float* __restrict__ pivot,
              const float* __restrict__ gmv,
              float* __restrict__ out) {
    const int t = blockIdx.x * 256 + threadIdx.x;
    const f32x4 pv = ((const f32x4*)pivot)[t & 15];     // lane-invariant d-slice
#pragma unroll
    for (int it = 0; it < K2IT; ++it) {
        const int i = t + it * (K2B * 256);             // float4 index
        const float g = gmv[i >> 4];                    // row = (i*4)/64
        const f32x4 z4 = ((const f32x4*)z)[i];
        f32x4 o;
        o.x = fmaf(g, pv.x - z4.x, z4.x);
        o.y = fmaf(g, pv.y - z4.y, z4.y);
        o.z = fmaf(g, pv.z - z4.z, z4.z);
        o.w = fmaf(g, pv.w - z4.w, z4.w);
        __builtin_nontemporal_store(o, &((f32x4*)out)[i]);
    }
}

// ============ fallback: round-3-style single fused kernel (proven) ==========
__global__ __launch_bounds__(256, 4)
void fused_constrain_fb(const float* __restrict__ z,
                        const float* __restrict__ pivot,
                        const float* __restrict__ At,
                        const float* __restrict__ b,
                        const float* __restrict__ ws,
                        float* __restrict__ out) {
    __shared__ __align__(16) char lds[33280];

    const int tid  = threadIdx.x;
    const int lane = tid & 63;
    const int li   = lane & 31;
    const int hi   = lane >> 5;
    const int wid  = tid >> 6;
    const int rg   = wid >> 1;
    const int cg   = wid & 1;
    const int R0   = rg * 32;
    const int colbase = cg * 128;
    const int base = blockIdx.x * (64 * DIMK);

    float4 zf[8];
    {
        const float* zr = z + base + (R0 + li) * DIMK + hi * 8;
#pragma unroll
        for (int q = 0; q < 4; ++q) {
            const float* p = zr + (q >> 1) * 32 + (q & 1) * 16;
            zf[q * 2 + 0] = *(const float4*)(p);
            zf[q * 2 + 1] = *(const float4*)(p + 4);
        }
    }
    const int swzT = (tid & 3) ^ ((tid >> 2) & 3);
#pragma unroll
    for (int kc = 0; kc < 4; ++kc) {
        float v[8];
#pragma unroll
        for (int j = 0; j < 8; ++j) v[j] = At[(kc * 8 + j) * MC + tid];
        half8 h, l;
#pragma unroll
        for (int j = 0; j < 8; ++j) {
            h[j] = (_Float16)v[j];
            l[j] = (_Float16)(v[j] - (float)h[j]);
        }
        const int off = tid * 64 + ((kc ^ swzT) << 4);
        *(half8*)(lds + LDS_AH + off) = h;
        *(half8*)(lds + LDS_AL + off) = l;
    }

    half8 azh[4], azl[4];
    const float* zv = (const float*)zf;
#pragma unroll
    for (int q = 0; q < 4; ++q)
        cvt_half8(zv + q * 8, azh[q], azl[q]);

    f32x16 acc[4];
#pragma unroll
    for (int ct = 0; ct < 4; ++ct)
#pragma unroll
        for (int e = 0; e < 16; ++e) acc[ct][e] = 0.f;

    const int swz = (li & 3) ^ ((li >> 2) & 3);
    __syncthreads();
#pragma unroll
    for (int ksl = 0; ksl < 2; ++ksl) {
        const int cb = ((ksl * 2 + hi) ^ swz) << 4;
        const half8 ah = azh[ksl], al = azl[ksl];
#pragma unroll
        for (int ct = 0; ct < 4; ++ct) {
            const int off = (colbase + ct * 32 + li) * 64 + cb;
            const half8 bh = *(const half8*)(lds + LDS_AH + off);
            const half8 bl = *(const half8*)(lds + LDS_AL + off);
            acc[ct] = __builtin_amdgcn_mfma_f32_32x32x16_f16(ah, bh, acc[ct], 0, 0, 0);
            acc[ct] = __builtin_amdgcn_mfma_f32_32x32x16_f16(ah, bl, acc[ct], 0, 0, 0);
            acc[ct] = __builtin_amdgcn_mfma_f32_32x32x16_f16(al, bh, acc[ct], 0, 0, 0);
        }
    }
    __syncthreads();
#pragma unroll
    for (int kc = 0; kc < 4; ++kc) {
        float v[8];
#pragma unroll
        for (int j = 0; j < 8; ++j) v[j] = At[(32 + kc * 8 + j) * MC + tid];
        half8 h, l;
#pragma unroll
        for (int j = 0; j < 8; ++j) {
            h[j] = (_Float16)v[j];
            l[j] = (_Float16)(v[j] - (float)h[j]);
        }
        const int off = tid * 64 + ((kc ^ swzT) << 4);
        *(half8*)(lds + LDS_AH + off) = h;
        *(half8*)(lds + LDS_AL + off) = l;
    }
    __syncthreads();
#pragma unroll
    for (int ksl = 0; ksl < 2; ++ksl) {
        const int cb = ((ksl * 2 + hi) ^ swz) << 4;
        const half8 ah = azh[2 + ksl], al = azl[2 + ksl];
#pragma unroll
        for (int ct = 0; ct < 4; ++ct) {
            const int off = (colbase + ct * 32 + li) * 64 + cb;
            const half8 bh = *(const half8*)(lds + LDS_AH + off);
            const half8 bl = *(const half8*)(lds + LDS_AL + off);
            acc[ct] = __builtin_amdgcn_mfma_f32_32x32x16_f16(ah, bh, acc[ct], 0, 0, 0);
            acc[ct] = __builtin_amdgcn_mfma_f32_32x32x16_f16(ah, bl, acc[ct], 0, 0, 0);
            acc[ct] = __builtin_amdgcn_mfma_f32_32x32x16_f16(al, bh, acc[ct], 0, 0, 0);
        }
    }

    float bv[4], cv[4];
#pragma unroll
    for (int ct = 0; ct < 4; ++ct) {
        const int c = colbase + ct * 32 + li;
        bv[ct] = b[c];
        cv[ct] = ws[c];
    }
    float gm[16];
#pragma unroll
    for (int r = 0; r < 16; ++r) gm[r] = 0.f;
#pragma unroll
    for (int ct = 0; ct < 4; ++ct)
#pragma unroll
        for (int r = 0; r < 16; ++r) {
            const float sv = acc[ct][r];
            const float sa = sv - bv[ct];
            const float qd = fmaxf(sv - cv[ct], 1e-9f);
            gm[r] = fmaxf(gm[r], sa * __builtin_amdgcn_rcpf(qd));
        }
#pragma unroll
    for (int r = 0; r < 16; ++r)
#pragma unroll
        for (int off = 1; off < 32; off <<= 1)
            gm[r] = fmaxf(gm[r], __shfl_xor(gm[r], off));

    float* gmbuf = (float*)(lds + LDS_GM);
#pragma unroll
    for (int r = 0; r < 16; ++r) {
        const int row = (r & 3) + 8 * (r >> 2) + 4 * hi;
        if (li == 0) gmbuf[rg * 64 + row * 2 + cg] = gm[r];
    }
    __syncthreads();

    const float2 p2 = *(const float2*)(pivot + 2 * li);
    const int r0 = cg * 8;
#pragma unroll
    for (int rr = 0; rr < 8; ++rr) {
        const int r   = r0 + rr;
        const int row = (r & 3) + 8 * (r >> 2) + 4 * hi;
        const float g = fmaxf(gm[r], gmbuf[rg * 64 + row * 2 + (cg ^ 1)]);
        const int idx = base + (R0 + row) * DIMK + 2 * li;
        const float2 zz = *(const float2*)(z + idx);
        float2 o;
        o.x = fmaf(g, p2.x - zz.x, zz.x);
        o.y = fmaf(g, p2.y - zz.y, zz.y);
        *(float2*)(out + idx) = o;
    }
}

extern "C" void kernel_launch(void* const* d_in, const int* in_sizes, int n_in,
                              void* d_out, int out_size, void* d_ws, size_t ws_size,
                              hipStream_t stream) {
    const float* z     = (const float*)d_in[0];
    const float* pivot = (const float*)d_in[1];
    const float* At    = (const float*)d_in[2];
    const float* b     = (const float*)d_in[3];
    float* ws = (float*)d_ws;
    if (ws_size >= (size_t)WS_NEED_SPLIT) {
        // split path: barrier-free GEMM+rowmax (sched-fenced, no spill) + apply
        float* gmv = (float*)((char*)d_ws + WS_GM);
        precompute_at<<<dim3(1), dim3(MC), 0, stream>>>(pivot, At, ws);
        k1_gemm_rowmax<<<dim3(K1B), dim3(256), 0, stream>>>(z, b, ws, gmv);
        k2_apply<<<dim3(K2B), dim3(256), 0, stream>>>(z, pivot, gmv,
                                                      (float*)d_out);
    } else {
        // safe path: 1 KB ws (cvec); per-block At split (proven structure)
        precompute_c<<<dim3(1), dim3(MC), 0, stream>>>(pivot, At, ws);
        fused_constrain_fb<<<dim3(NROWS / 64), dim3(256), 0, stream>>>(
            z, pivot, At, b, ws, (float*)d_out);
    }
}